// Round 5
// baseline (26090.561 us; speedup 1.0000x reference)
//
#include <hip/hip_runtime.h>
#include <math.h>

// LSTMEncoder: B=64,S=512,F=128,D=512,U=1024
// One persistent cooperative kernel runs all 512 timesteps; grid barrier between
// steps. z = bf + x_t@Wf + h@Wh, gates i,f,g,o (Keras), c,h update.
// Weights gate-packed W4[k][u][4] so inner iter = 2 float4 loads + 16 FMA.

#define BB 64
#define SS 512
#define FF 128
#define DD 512
#define UU 1024
#define GG 4096  // 4*U
#define NBLK 256

__device__ __forceinline__ float sigmoidf_(float v) {
    return 1.0f / (1.0f + __expf(-v));
}
__device__ __forceinline__ float tanhf_(float v) {
    float e = __expf(2.0f * v);          // inf-safe: 1 - 2/(e+1)
    return 1.0f - 2.0f / (e + 1.0f);
}

// Wf4[f][u][gate] = sum_d dense_W[f][d] * Wx[d][gate*UU+u]
__global__ __launch_bounds__(256) void fuse_w(const float* __restrict__ dW,
                                              const float* __restrict__ Wx,
                                              float* __restrict__ Wf4) {
    int tid = blockIdx.x * 256 + threadIdx.x;   // 128*4096
    int gcol = tid & (GG - 1);
    int f = tid >> 12;
    const float* wr = dW + f * DD;
    float acc = 0.0f;
#pragma unroll 4
    for (int d = 0; d < DD; ++d)
        acc = fmaf(wr[d], Wx[(size_t)d * GG + gcol], acc);
    Wf4[((size_t)f * UU + (gcol & (UU - 1))) * 4 + (gcol >> 10)] = acc;
}

// bf[g] = sum_d dense_b[d] * Wx[d][g] + b[g]   (kept gate-major [4][UU])
__global__ __launch_bounds__(256) void fuse_b(const float* __restrict__ db,
                                              const float* __restrict__ Wx,
                                              const float* __restrict__ bias,
                                              float* __restrict__ bf) {
    int g = blockIdx.x * 256 + threadIdx.x;     // 4096
    float acc = bias[g];
#pragma unroll 4
    for (int d = 0; d < DD; ++d)
        acc = fmaf(db[d], Wx[(size_t)d * GG + g], acc);
    bf[g] = acc;
}

// Wh[k][gate*UU+u] -> Wh4[k][u][gate]
__global__ __launch_bounds__(256) void repack_wh(const float* __restrict__ Wh,
                                                 float* __restrict__ Wh4) {
    size_t tid = (size_t)blockIdx.x * 256 + threadIdx.x;   // 4M
    int gcol = (int)(tid & (GG - 1));
    int k = (int)(tid >> 12);
    Wh4[((size_t)k * UU + (gcol & (UU - 1))) * 4 + (gcol >> 10)] = Wh[tid];
}

// x[b][s][k] -> xT[s][k][b]
__global__ __launch_bounds__(256) void transpose_x(const float* __restrict__ x,
                                                   float* __restrict__ xT) {
    __shared__ float xs[64 * 129];
    const int s = blockIdx.x;                    // 0..511
    for (int i = threadIdx.x; i < 64 * 128; i += 256) {
        int b = i >> 7, k = i & 127;
        xs[b * 129 + k] = x[((size_t)b * SS + s) * FF + k];
    }
    __syncthreads();
    for (int i = threadIdx.x; i < 64 * 128; i += 256) {
        int k = i >> 6, b = i & 63;
        xT[((size_t)s * FF + k) * 64 + b] = xs[b * 129 + k];
    }
}

__device__ __forceinline__ void fma16(float (&acc)[4][4], float4 h4, float4 w4) {
    acc[0][0] = fmaf(h4.x, w4.x, acc[0][0]);
    acc[0][1] = fmaf(h4.x, w4.y, acc[0][1]);
    acc[0][2] = fmaf(h4.x, w4.z, acc[0][2]);
    acc[0][3] = fmaf(h4.x, w4.w, acc[0][3]);
    acc[1][0] = fmaf(h4.y, w4.x, acc[1][0]);
    acc[1][1] = fmaf(h4.y, w4.y, acc[1][1]);
    acc[1][2] = fmaf(h4.y, w4.z, acc[1][2]);
    acc[1][3] = fmaf(h4.y, w4.w, acc[1][3]);
    acc[2][0] = fmaf(h4.z, w4.x, acc[2][0]);
    acc[2][1] = fmaf(h4.z, w4.y, acc[2][1]);
    acc[2][2] = fmaf(h4.z, w4.z, acc[2][2]);
    acc[2][3] = fmaf(h4.z, w4.w, acc[2][3]);
    acc[3][0] = fmaf(h4.w, w4.x, acc[3][0]);
    acc[3][1] = fmaf(h4.w, w4.y, acc[3][1]);
    acc[3][2] = fmaf(h4.w, w4.z, acc[3][2]);
    acc[3][3] = fmaf(h4.w, w4.w, acc[3][3]);
}

// Device-scope grid barrier: bar[0]=arrive counter, bar[1]=generation.
__device__ __forceinline__ void grid_barrier(unsigned* bar) {
    __syncthreads();                 // all waves done; stores drained (vmcnt)
    if (threadIdx.x == 0) {
        __threadfence();             // agent-scope release (cross-XCD wb)
        unsigned g = __hip_atomic_load(&bar[1], __ATOMIC_SEQ_CST, __HIP_MEMORY_SCOPE_AGENT);
        unsigned old = __hip_atomic_fetch_add(&bar[0], 1u, __ATOMIC_SEQ_CST, __HIP_MEMORY_SCOPE_AGENT);
        if (old == NBLK - 1) {
            __hip_atomic_store(&bar[0], 0u, __ATOMIC_RELAXED, __HIP_MEMORY_SCOPE_AGENT);
            __hip_atomic_store(&bar[1], g + 1u, __ATOMIC_RELEASE, __HIP_MEMORY_SCOPE_AGENT);
        } else {
            while (__hip_atomic_load(&bar[1], __ATOMIC_RELAXED, __HIP_MEMORY_SCOPE_AGENT) == g)
                __builtin_amdgcn_s_sleep(2);
        }
        __threadfence();             // acquire side (cross-XCD inv)
    }
    __syncthreads();
}

// Persistent kernel: 256 blocks x 1024 thr. Block = (utile 16u, btile 16b).
// 16 waves: wave = 64-k slice of h-K (+8-k slice of x-K). Lane: u_l=lane&15,
// bgrp=lane>>4 -> 4 b's. acc[b][gate]; weights float4 (gate-packed), h/x float4.
__global__ __launch_bounds__(1024, 4) void lstm_persist(
    const float* __restrict__ xT,     // [SS][FF][64]
    const float* __restrict__ Wh4,    // [1024k][1024u][4]
    const float* __restrict__ Wf4,    // [128k][1024u][4]
    const float* __restrict__ bfb,    // [4][1024]
    float* __restrict__ out,          // [64][512][1024]
    float* __restrict__ cbuf,         // [1024u][64b]
    float* h0, float* h1,             // parity buffers [1024k][64b]
    unsigned* bar) {
    __shared__ __align__(16) float zl[8 * 1024];   // 32 KB
    __shared__ float zr[1024];                     // 4 KB

    const int utile = blockIdx.x & 63;
    const int btile = blockIdx.x >> 6;
    const int u0 = utile * 16;
    const int wid  = threadIdx.x >> 6;
    const int lane = threadIdx.x & 63;
    const int u_l  = lane & 15;
    const int bgrp = lane >> 4;
    const int bbase = btile * 16 + bgrp * 4;

    const float* wfx = Wf4 + ((size_t)(wid * 8) * UU + u0 + u_l) * 4;
    const float* whb = Wh4 + ((size_t)(wid * 64) * UU + u0 + u_l) * 4;

    for (int t = 0; t < SS; ++t) {
        const float* hprev = (t & 1) ? h0 : h1;
        float* hnext       = (t & 1) ? h1 : h0;

        float acc[4][4];
#pragma unroll
        for (int i = 0; i < 4; ++i)
#pragma unroll
            for (int g = 0; g < 4; ++g) acc[i][g] = 0.0f;

        // x part: k in [wid*8, wid*8+8)
        {
            const float* xp = xT + ((size_t)t * FF + wid * 8) * 64 + bbase;
            const float* wp = wfx;
#pragma unroll 2
            for (int k = 0; k < 8; ++k) {
                float4 h4 = *(const float4*)xp;
                float4 w4 = *(const float4*)wp;
                fma16(acc, h4, w4);
                xp += 64;
                wp += UU * 4;
            }
        }
        // h part: k in [wid*64, wid*64+64)
        if (t > 0) {
            const float* hp = hprev + (size_t)(wid * 64) * 64 + bbase;
            const float* wp = whb;
#pragma unroll 4
            for (int k = 0; k < 64; ++k) {
                float4 h4 = *(const float4*)hp;
                float4 w4 = *(const float4*)wp;
                fma16(acc, h4, w4);
                hp += 64;
                wp += UU * 4;
            }
        }

        // reduce: waves 0-7 write, waves 8-15 add, then 8-way tree
        if (wid < 8) {
#pragma unroll
            for (int g = 0; g < 4; ++g)
                *(float4*)&zl[wid * 1024 + g * 256 + u_l * 16 + bgrp * 4] =
                    make_float4(acc[0][g], acc[1][g], acc[2][g], acc[3][g]);
        }
        __syncthreads();
        if (wid >= 8) {
#pragma unroll
            for (int g = 0; g < 4; ++g) {
                float* p = &zl[(wid - 8) * 1024 + g * 256 + u_l * 16 + bgrp * 4];
                float4 v = *(float4*)p;
                v.x += acc[0][g]; v.y += acc[1][g]; v.z += acc[2][g]; v.w += acc[3][g];
                *(float4*)p = v;
            }
        }
        __syncthreads();
        {
            float v = 0.0f;
#pragma unroll
            for (int w = 0; w < 8; ++w) v += zl[w * 1024 + threadIdx.x];
            zr[threadIdx.x] = v;
        }
        __syncthreads();

        if (threadIdx.x < 256) {
            const int bl = threadIdx.x >> 4;
            const int ul = threadIdx.x & 15;
            const int bb = btile * 16 + bl;
            const int uu = u0 + ul;

            float z0 = zr[0 * 256 + ul * 16 + bl] + bfb[uu];
            float z1 = zr[1 * 256 + ul * 16 + bl] + bfb[uu + UU];
            float z2 = zr[2 * 256 + ul * 16 + bl] + bfb[uu + 2 * UU];
            float z3 = zr[3 * 256 + ul * 16 + bl] + bfb[uu + 3 * UU];

            float iv = sigmoidf_(z0);
            float fv = sigmoidf_(z1);
            float gv = tanhf_(z2);
            float ov = sigmoidf_(z3);

            float* cp = cbuf + (size_t)uu * 64 + bb;
            float cv = fv * (*cp) + iv * gv;
            *cp = cv;
            float hv = ov * tanhf_(cv);

            out[((size_t)bb * SS + t) * UU + uu] = hv;
            hnext[(size_t)uu * 64 + bb] = hv;
        }

        if (t != SS - 1) grid_barrier(bar);
    }
}

extern "C" void kernel_launch(void* const* d_in, const int* in_sizes, int n_in,
                              void* d_out, int out_size, void* d_ws, size_t ws_size,
                              hipStream_t stream) {
    const float* x    = (const float*)d_in[0];   // [64,512,128]
    const float* dW   = (const float*)d_in[1];   // [128,512]
    const float* db   = (const float*)d_in[2];   // [512]
    const float* Wx   = (const float*)d_in[3];   // [512,4096]
    const float* Wh   = (const float*)d_in[4];   // [1024,4096]
    const float* bias = (const float*)d_in[5];   // [4096]
    float* out = (float*)d_out;                  // [64,512,1024]

    char* ws = (char*)d_ws;
    size_t off = 0;
    float* Wh4 = (float*)(ws + off); off += (size_t)UU * UU * 4 * 4;   // 16 MB
    float* xT  = (float*)(ws + off); off += (size_t)SS * FF * 64 * 4;  // 16 MB
    float* Wf4 = (float*)(ws + off); off += (size_t)FF * UU * 4 * 4;   // 2 MB
    float* bf  = (float*)(ws + off); off += (size_t)GG * 4;            // 16 KB
    float* cbuf = (float*)(ws + off); off += (size_t)BB * UU * 4;      // 256 KB
    float* h0  = (float*)(ws + off); off += (size_t)BB * UU * 4;       // 256 KB
    float* h1  = (float*)(ws + off); off += (size_t)BB * UU * 4;       // 256 KB
    unsigned* bar = (unsigned*)(ws + off);                             // 8 B

    hipMemsetAsync(cbuf, 0, (size_t)BB * UU * 4, stream);
    hipMemsetAsync(bar, 0, 2 * sizeof(unsigned), stream);
    fuse_w<<<(FF * GG) / 256, 256, 0, stream>>>(dW, Wx, Wf4);
    fuse_b<<<GG / 256, 256, 0, stream>>>(db, Wx, bias, bf);
    repack_wh<<<(UU * GG) / 256, 256, 0, stream>>>(Wh, Wh4);
    transpose_x<<<SS, 256, 0, stream>>>(x, xT);

    void* args[] = {(void*)&xT, (void*)&Wh4, (void*)&Wf4, (void*)&bf, (void*)&out,
                    (void*)&cbuf, (void*)&h0, (void*)&h1, (void*)&bar};
    hipLaunchCooperativeKernel((void*)lstm_persist, dim3(NBLK), dim3(1024), args, 0, stream);
}